// Round 1
// baseline (138.889 us; speedup 1.0000x reference)
//
#include <hip/hip_runtime.h>
#include <hip/hip_bf16.h>

// RecallCELoss: the reference computes
//   loss = -mean((1 - recall) * nc * log(pc))   with pc == ones
// log(1.0) == 0.0 exactly, every other factor is finite, so the loss is
// identically 0.0 for ALL inputs (the reference's own comment says so).
// The argmax / segment_sum pipeline is dead code w.r.t. the output.
// Optimal kernel: store a single float32 zero to d_out.

__global__ void RecallCELoss_35734127902813_kernel(float* __restrict__ out,
                                                   int out_size) {
    // One wave; lane 0..out_size-1 write the constant result (out_size == 1
    // for the scalar loss, but handle any small out_size defensively since
    // d_out is re-poisoned to 0xAA before every timed launch).
    int i = threadIdx.x;
    if (i < out_size) {
        out[i] = 0.0f;
    }
}

extern "C" void kernel_launch(void* const* d_in, const int* in_sizes, int n_in,
                              void* d_out, int out_size, void* d_ws, size_t ws_size,
                              hipStream_t stream) {
    (void)d_in; (void)in_sizes; (void)n_in; (void)d_ws; (void)ws_size;
    float* out = (float*)d_out;
    // Single 64-thread block (one wave) — minimum launch quantum on CDNA.
    RecallCELoss_35734127902813_kernel<<<1, 64, 0, stream>>>(out, out_size);
}